// Round 1
// baseline (4475.542 us; speedup 1.0000x reference)
//
#include <hip/hip_runtime.h>
#include <cstdint>
#include <cstddef>

// B=32, S=512, I=256, H=512, E=1024, NH=16, HD=64
// Key structural facts exploited (verified against the reference einsums):
//  - Only out[:, -1, :] feeds the final FC; due to the reshape scramble this
//    is attention head 15 at positions s in [496, 512).
//  - Backward LSTM therefore only needs its first 16 steps.
//  - Wo/Wfc fold into w_eff[1024]; w_eff-contracted Wv folds into wv2.
// Critical path: 512 sequential forward-LSTM steps -> persistent kernel with
// hand-rolled device-scope barriers, weight-stationary fp16 MFMA fragments.

typedef _Float16 v8h __attribute__((ext_vector_type(8)));
typedef _Float16 v4h __attribute__((ext_vector_type(4)));
typedef float    v4f __attribute__((ext_vector_type(4)));

// ---- workspace layout (bytes), all offsets 256B aligned ----
static constexpr size_t OFF_CNT   = 0;                        // 3 x u32: cnt_f, cnt_b, done
static constexpr size_t OFF_LOGIT = 256;                      // 32 floats
static constexpr size_t OFF_HFB   = 1024;                     // fwd h dbl buf: 2*32*512 f16
static constexpr size_t OFF_HBB   = 66560;                    // bwd h dbl buf
static constexpr size_t ZERO_BYTES= 132096;                   // memset span
static constexpr size_t OFF_WHHF  = 132096;                   // 2048x512 f16
static constexpr size_t OFF_WIHF  = OFF_WHHF + 2048ull*512*2; // 2048x256 f16
static constexpr size_t OFF_WHHB  = OFF_WIHF + 2048ull*256*2;
static constexpr size_t OFF_WIHB  = OFF_WHHB + 2048ull*512*2;
static constexpr size_t OFF_HIST  = OFF_WIHB + 2048ull*256*2; // 32*16*1024 f32
static constexpr size_t OFF_WKT   = OFF_HIST + 32ull*16*1024*4;  // 1024x1024 f16 (WkT[e][j])
static constexpr size_t OFF_WQT   = OFF_WKT + 1024ull*1024*2;    // 1024x64 f16 (WqT15[e][d])
static constexpr size_t OFF_WV2   = OFF_WQT + 1024ull*64*2;      // 16*1024*16 f32 wv2T[r][e][kh]
static constexpr size_t OFF_CV    = OFF_WV2 + 16ull*1024*16*4;   // 16*16 f32
static constexpr size_t OFF_BEFF  = OFF_CV + 1024;               // 1 f32
static constexpr size_t OFF_WEFF  = OFF_BEFF + 256;              // 1024 f32
// total ~11.3 MB

static constexpr int PANEL_STRIDE = 776;   // 768 + 8 f16 pad (bank de-phase)
static constexpr int DYN_LDS      = 53504;

// -------------------- prep kernels --------------------

__global__ void k_convert(const float* __restrict__ whhf, const float* __restrict__ wihf,
                          const float* __restrict__ whhb, const float* __restrict__ wihb,
                          char* __restrict__ ws)
{
    _Float16* o1 = (_Float16*)(ws + OFF_WHHF);
    _Float16* o2 = (_Float16*)(ws + OFF_WIHF);
    _Float16* o3 = (_Float16*)(ws + OFF_WHHB);
    _Float16* o4 = (_Float16*)(ws + OFF_WIHB);
    const int stride = gridDim.x * blockDim.x;
    for (int i = blockIdx.x*blockDim.x + threadIdx.x; i < 2048*512; i += stride) {
        o1[i] = (_Float16)whhf[i];
        o3[i] = (_Float16)whhb[i];
    }
    for (int i = blockIdx.x*blockDim.x + threadIdx.x; i < 2048*256; i += stride) {
        o2[i] = (_Float16)wihf[i];
        o4[i] = (_Float16)wihb[i];
    }
}

// w_eff[e2] = sum_e Wfc[e]*Wo[e][e2];  b_eff = Wfc.bo + bfc
__global__ void k_weff(const float* __restrict__ Wfc, const float* __restrict__ Wo,
                       const float* __restrict__ bo, const float* __restrict__ bfc,
                       char* __restrict__ ws)
{
    float* weff = (float*)(ws + OFF_WEFF);
    float* beff = (float*)(ws + OFF_BEFF);
    const int e2 = blockIdx.x*256 + threadIdx.x;   // grid 4 -> 1024
    float a = 0.f;
    for (int e = 0; e < 1024; ++e) a += Wfc[e] * Wo[(size_t)e*1024 + e2];
    weff[e2] = a;
    if (e2 == 0) {
        float b = bfc[0];
        for (int e = 0; e < 1024; ++e) b += Wfc[e]*bo[e];
        beff[0] = b;
    }
}

// wv2T[r][e][kh] = sum_hd w_eff[64r+hd]*Wv[64kh+hd][e];  cv[r][kh] = w_eff slice . bv slice
__global__ void k_wv2(const float* __restrict__ Wv, const float* __restrict__ bv,
                      char* __restrict__ ws)
{
    const float* weff = (const float*)(ws + OFF_WEFF);
    float* wv2 = (float*)(ws + OFF_WV2);
    float* cv  = (float*)(ws + OFF_CV);
    const int gid = blockIdx.x*256 + threadIdx.x;  // grid 64 -> 16384
    const int e = gid >> 4, kh = gid & 15;
    float col[64];
    for (int hd = 0; hd < 64; ++hd) col[hd] = Wv[((size_t)(kh*64 + hd))*1024 + e];
    for (int r = 0; r < 16; ++r) {
        float a = 0.f;
        for (int hd = 0; hd < 64; ++hd) a += weff[r*64 + hd] * col[hd];
        wv2[((size_t)r*1024 + e)*16 + kh] = a;
    }
    if (gid < 256) {
        const int r2 = gid >> 4, k2 = gid & 15;
        float a = 0.f;
        for (int hd = 0; hd < 64; ++hd) a += weff[r2*64 + hd] * bv[k2*64 + hd];
        cv[gid] = a;
    }
}

// WkT[e][j] = Wk[j][e], fp16
__global__ void k_tk(const float* __restrict__ Wk, char* __restrict__ ws)
{
    _Float16* WkT = (_Float16*)(ws + OFF_WKT);
    __shared__ float tile[32][33];
    const int jt = blockIdx.x & 31, et = blockIdx.x >> 5;   // 1024 blocks
    const int tx = threadIdx.x & 31, ty = threadIdx.x >> 5; // 32x8
    for (int i = 0; i < 4; ++i)
        tile[ty + 8*i][tx] = Wk[((size_t)(jt*32 + ty + 8*i))*1024 + et*32 + tx];
    __syncthreads();
    for (int i = 0; i < 4; ++i)
        WkT[((size_t)(et*32 + ty + 8*i))*1024 + jt*32 + tx] = (_Float16)tile[tx][ty + 8*i];
}

// WqT15[e][d] = Wq[960+d][e], fp16
__global__ void k_tq(const float* __restrict__ Wq, char* __restrict__ ws)
{
    _Float16* WqT = (_Float16*)(ws + OFF_WQT);
    const int gid = blockIdx.x*256 + threadIdx.x;  // 256 blocks -> 65536
    const int d = gid & 63, e = gid >> 6;
    WqT[e*64 + d] = (_Float16)Wq[((size_t)(960 + d))*1024 + e];
}

// -------------------- main persistent kernel --------------------
// grid = 64 WGs x 256 threads. WG 0..31: forward LSTM (512 steps),
// WG 32..63: backward LSTM (16 steps). Each WG owns 16 h-columns.
// Then all 64 WGs compute the collapsed attention epilogue.

__global__ __launch_bounds__(256, 1)
void bilstm_main(const float* __restrict__ xg,
                 const float* __restrict__ b_f, const float* __restrict__ b_b,
                 const float* __restrict__ bq,  const float* __restrict__ bk,
                 char* __restrict__ ws, float* __restrict__ out)
{
    extern __shared__ char smem[];

    const int tid  = threadIdx.x;
    const int wgid = blockIdx.x;
    const int wave = tid >> 6;
    const int lane = tid & 63;
    const int quad = lane >> 4;
    const int l16  = lane & 15;
    const int dir  = wgid >> 5;            // 0 fwd, 1 bwd
    const int col0 = (wgid & 31) * 16;

    unsigned* cnts  = (unsigned*)(ws + OFF_CNT);
    float*   logits = (float*)(ws + OFF_LOGIT);
    _Float16* hbase = (_Float16*)(ws + (dir ? OFF_HBB : OFF_HFB));
    const _Float16* whh = (const _Float16*)(ws + (dir ? OFF_WHHB : OFF_WHHF));
    const _Float16* wih = (const _Float16*)(ws + (dir ? OFF_WIHB : OFF_WIHF));
    float* hist = (float*)(ws + OFF_HIST);
    unsigned* cnt = cnts + dir;

    _Float16* panel = (_Float16*)smem;     // [32][776] f16 A-panel; gates alias it
    float* gates = (float*)smem;           // [64][132] f32: [n][b*4 + wave]

    // persistent B fragments: W rows (gate nt) x K=768 ([Whh | Wih]), wave = K-quarter
    v8h bfrag[4][6];
#pragma unroll
    for (int nt = 0; nt < 4; ++nt)
#pragma unroll
        for (int kk = 0; kk < 6; ++kk) {
            const int kb = (wave*6 + kk)*32 + quad*8;
            const int r  = nt*512 + col0 + l16;
            const _Float16* src = (kb < 512) ? (whh + (size_t)r*512 + kb)
                                             : (wih + (size_t)r*256 + (kb - 512));
            bfrag[nt][kk] = *(const v8h*)src;
        }

    // activation role: column ac = tid&15, batches ab and ab+16
    const float* bias = dir ? b_b : b_f;
    const int ac = tid & 15;
    const int ab = tid >> 4;
    float bia[4];
#pragma unroll
    for (int g = 0; g < 4; ++g) bia[g] = bias[g*512 + col0 + ac];

    float cst[2] = {0.f, 0.f};
    const int nsteps  = dir ? 16 : 512;
    const int histoff = dir ? 512 : 0;

    for (int t = 0; t < nsteps; ++t) {
        const int s = dir ? (511 - t) : t;
        // barrier: wait for all 32 WGs of this direction to finish step t-1
        if (tid == 0) {
            const unsigned target = 32u * (unsigned)t;
            while (__hip_atomic_load(cnt, __ATOMIC_RELAXED, __HIP_MEMORY_SCOPE_AGENT) < target) {}
            __threadfence();  // acquire: invalidate stale L1/L2 (cross-XCD h)
        }
        __syncthreads();

        // stage h_{t-1} (f16) into panel cols [0,512)
        const _Float16* rbuf = hbase + ((size_t)((t+1)&1))*(32*512);
#pragma unroll
        for (int i = 0; i < 8; ++i) {
            const int ch = tid + 256*i; const int b = ch >> 6, kc = ch & 63;
            *(v8h*)(panel + b*PANEL_STRIDE + kc*8) = *(const v8h*)(rbuf + b*512 + kc*8);
        }
        // stage x[:, s, :] (f32 -> f16) into panel cols [512,768)
#pragma unroll
        for (int i = 0; i < 8; ++i) {
            const int ch = tid + 256*i; const int b = ch >> 6, ic = ch & 63;
            const float4 xv = *(const float4*)(xg + ((size_t)b*512 + s)*256 + ic*4);
            v4h hx = { (_Float16)xv.x, (_Float16)xv.y, (_Float16)xv.z, (_Float16)xv.w };
            *(v4h*)(panel + b*PANEL_STRIDE + 512 + ic*4) = hx;
        }
        __syncthreads();

        // GEMM: gates[b(32)][n(64)] += A[b][k(768)] * W[n][k], K split 4-way by wave
        v4f acc[2][4];
#pragma unroll
        for (int mt = 0; mt < 2; ++mt)
#pragma unroll
            for (int nt = 0; nt < 4; ++nt) { v4f z = {0.f,0.f,0.f,0.f}; acc[mt][nt] = z; }
#pragma unroll
        for (int kk = 0; kk < 6; ++kk) {
            const int kb = (wave*6 + kk)*32 + quad*8;
            const v8h a0 = *(const v8h*)(panel + l16*PANEL_STRIDE + kb);
            const v8h a1 = *(const v8h*)(panel + (16 + l16)*PANEL_STRIDE + kb);
#pragma unroll
            for (int nt = 0; nt < 4; ++nt) {
                acc[0][nt] = __builtin_amdgcn_mfma_f32_16x16x32_f16(a0, bfrag[nt][kk], acc[0][nt], 0, 0, 0);
                acc[1][nt] = __builtin_amdgcn_mfma_f32_16x16x32_f16(a1, bfrag[nt][kk], acc[1][nt], 0, 0, 0);
            }
        }
        __syncthreads();   // panel reads done before gates alias-write

        // write K-partials: gates[n][b][wave], n-stride 132 floats
#pragma unroll
        for (int mt = 0; mt < 2; ++mt)
#pragma unroll
            for (int nt = 0; nt < 4; ++nt)
#pragma unroll
                for (int r = 0; r < 4; ++r)
                    gates[(nt*16 + l16)*132 + (mt*16 + quad*4 + r)*4 + wave] = acc[mt][nt][r];
        __syncthreads();

        // activations: thread owns (b=ab, c=ac) and (b=ab+16, c=ac)
        _Float16* wbuf = hbase + ((size_t)(t&1))*(32*512);
#pragma unroll
        for (int hh = 0; hh < 2; ++hh) {
            const int b = ab + 16*hh;
            float g[4];
#pragma unroll
            for (int gi = 0; gi < 4; ++gi) {
                const v4f v = *(const v4f*)(gates + (gi*16 + ac)*132 + b*4);
                g[gi] = v.x + v.y + v.z + v.w + bia[gi];
            }
            const float ig = 1.f/(1.f + __expf(-g[0]));
            const float fg = 1.f/(1.f + __expf(-g[1]));
            const float gg = 1.f - 2.f/(__expf(2.f*g[2]) + 1.f);
            const float og = 1.f/(1.f + __expf(-g[3]));
            cst[hh] = fg*cst[hh] + ig*gg;
            const float hn = og * (1.f - 2.f/(__expf(2.f*cst[hh]) + 1.f));
            wbuf[b*512 + col0 + ac] = (_Float16)hn;
            if (s >= 496)
                hist[((size_t)b*16 + (s - 496))*1024 + histoff + col0 + ac] = hn;
        }
        __syncthreads();   // drains vmcnt for all waves before release
        if (tid == 0) {
            __threadfence();  // release: write back L2 so other XCDs can see h
            __hip_atomic_fetch_add(cnt, 1u, __ATOMIC_RELAXED, __HIP_MEMORY_SCOPE_AGENT);
        }
    }

    // join: wait for both directions fully done
    if (tid == 0) {
        while (__hip_atomic_load(cnts + 0, __ATOMIC_RELAXED, __HIP_MEMORY_SCOPE_AGENT) < 32u*512u ||
               __hip_atomic_load(cnts + 1, __ATOMIC_RELAXED, __HIP_MEMORY_SCOPE_AGENT) < 32u*16u) {}
        __threadfence();
    }
    __syncthreads();

    // ---------------- collapsed attention epilogue ----------------
    // pairs p = 8*wgid .. 8*wgid+7;  p -> (b = p>>4, r = p&15, s' = 496+r)
    float*    hv  = (float*)smem;                 // [8][1024]
    _Float16* k16 = (_Float16*)(smem + 32768);    // [8][1024]
    float*    qb  = (float*)(smem + 49152);       // [8][64]
    float*    vzb = (float*)(smem + 51200);       // [8][16]
    float*    scb = (float*)(smem + 51712);       // [8][16]
    int*      lastf = (int*)(smem + 53248);

    const _Float16* WkT = (const _Float16*)(ws + OFF_WKT);
    const _Float16* WqT = (const _Float16*)(ws + OFF_WQT);
    const float* wv2 = (const float*)(ws + OFF_WV2);
    const float* cv  = (const float*)(ws + OFF_CV);
    const float* beff= (const float*)(ws + OFF_BEFF);

    const int p0 = wgid * 8;
#pragma unroll
    for (int i = 0; i < 8; ++i) {
        const int ch = tid + 256*i;            // 2048 float4 chunks
        const int pp = ch >> 8, e4 = ch & 255;
        const int p = p0 + pp; const int b = p >> 4, r = p & 15;
        *(float4*)(hv + pp*1024 + e4*4) =
            *(const float4*)(hist + ((size_t)b*16 + r)*1024 + e4*4);
    }
    __syncthreads();

    // K projection: k[pp][j] over j = jj*256+tid
    float kacc[4][8];
#pragma unroll
    for (int jj = 0; jj < 4; ++jj) {
        const float bkv = bk[jj*256 + tid];
#pragma unroll
        for (int pp = 0; pp < 8; ++pp) kacc[jj][pp] = bkv;
    }
    for (int e = 0; e < 1024; ++e) {
        float hvv[8];
#pragma unroll
        for (int pp = 0; pp < 8; ++pp) hvv[pp] = hv[pp*1024 + e];
#pragma unroll
        for (int jj = 0; jj < 4; ++jj) {
            const float w = (float)WkT[(size_t)e*1024 + jj*256 + tid];
#pragma unroll
            for (int pp = 0; pp < 8; ++pp) kacc[jj][pp] += w * hvv[pp];
        }
    }
#pragma unroll
    for (int jj = 0; jj < 4; ++jj)
#pragma unroll
        for (int pp = 0; pp < 8; ++pp)
            k16[pp*1024 + jj*256 + tid] = (_Float16)kacc[jj][pp];

    // Q head 15
    {
        const int d = tid & 63, ph = tid >> 6;
        float a0 = bq[960 + d], a1 = a0;
        for (int e = 0; e < 1024; ++e) {
            const float w = (float)WqT[e*64 + d];
            a0 += w * hv[ph*1024 + e];
            a1 += w * hv[(ph+4)*1024 + e];
        }
        qb[ph*64 + d] = a0;
        qb[(ph+4)*64 + d] = a1;
    }
    // vz[pp][kh] = cv + sum_e wv2T[r][e][kh]*hv[pp][e]
    if (tid < 128) {
        const int pp = tid >> 4, kh = tid & 15;
        const int r = (p0 + pp) & 15;
        float a = cv[r*16 + kh];
        for (int e = 0; e < 1024; ++e)
            a += wv2[((size_t)r*1024 + e)*16 + kh] * hv[pp*1024 + e];
        vzb[pp*16 + kh] = a;
    }
    __syncthreads();
    // scores
    if (tid < 128) {
        const int pp = tid >> 4, kh = tid & 15;
        float a = 0.f;
#pragma unroll
        for (int d = 0; d < 64; ++d)
            a += qb[pp*64 + d] * (float)k16[pp*1024 + kh*64 + d];
        scb[pp*16 + kh] = a * 0.125f;  // 1/sqrt(64)
    }
    __syncthreads();
    // softmax over kh + contract with vz, accumulate into logits[b]
    if (tid < 8) {
        const int base = tid*16;
        float m = scb[base];
        for (int kh = 1; kh < 16; ++kh) m = fmaxf(m, scb[base+kh]);
        float sum = 0.f, wz = 0.f;
        for (int kh = 0; kh < 16; ++kh) {
            const float pe = __expf(scb[base+kh] - m);
            sum += pe; wz += pe * vzb[base+kh];
        }
        atomicAdd(&logits[(p0 + tid) >> 4], wz / sum);
    }
    __syncthreads();  // drains the atomics (vmcnt) before done-count
    if (tid == 0) {
        const unsigned old = __hip_atomic_fetch_add(cnts + 2, 1u, __ATOMIC_ACQ_REL, __HIP_MEMORY_SCOPE_AGENT);
        *lastf = (old == 63u) ? 1 : 0;
    }
    __syncthreads();
    if (*lastf) {                       // WG-uniform branch
        if (tid == 0) __threadfence();  // acquire all WGs' logit adds
        __syncthreads();
        if (tid < 32) {
            const float lg = logits[tid] + beff[0];
            out[tid] = 1.f/(1.f + __expf(-lg));
        }
    }
}

// -------------------- launcher --------------------

extern "C" void kernel_launch(void* const* d_in, const int* in_sizes, int n_in,
                              void* d_out, int out_size, void* d_ws, size_t ws_size,
                              hipStream_t stream)
{
    (void)in_sizes; (void)n_in; (void)out_size; (void)ws_size;
    const float* x    = (const float*)d_in[0];
    const float* Wihf = (const float*)d_in[1];
    const float* Whhf = (const float*)d_in[2];
    const float* b_f  = (const float*)d_in[3];
    const float* Wihb = (const float*)d_in[4];
    const float* Whhb = (const float*)d_in[5];
    const float* b_b  = (const float*)d_in[6];
    const float* Wq   = (const float*)d_in[7];
    const float* bq   = (const float*)d_in[8];
    const float* Wk   = (const float*)d_in[9];
    const float* bk   = (const float*)d_in[10];
    const float* Wv   = (const float*)d_in[11];
    const float* bv   = (const float*)d_in[12];
    const float* Wo   = (const float*)d_in[13];
    const float* bo   = (const float*)d_in[14];
    const float* Wfc  = (const float*)d_in[15];
    const float* bfc  = (const float*)d_in[16];
    char* ws = (char*)d_ws;
    float* out = (float*)d_out;

    // zero counters + logits + h double buffers (ws is poisoned 0xAA each call)
    hipMemsetAsync(ws, 0, ZERO_BYTES, stream);
    hipLaunchKernelGGL(k_convert, dim3(512), dim3(256), 0, stream, Whhf, Wihf, Whhb, Wihb, ws);
    hipLaunchKernelGGL(k_weff,    dim3(4),   dim3(256), 0, stream, Wfc, Wo, bo, bfc, ws);
    hipLaunchKernelGGL(k_wv2,     dim3(64),  dim3(256), 0, stream, Wv, bv, ws);
    hipLaunchKernelGGL(k_tk,      dim3(1024),dim3(256), 0, stream, Wk, ws);
    hipLaunchKernelGGL(k_tq,      dim3(256), dim3(256), 0, stream, Wq, ws);
    hipLaunchKernelGGL(bilstm_main, dim3(64), dim3(256), DYN_LDS, stream,
                       x, b_f, b_b, bq, bk, ws, out);
}

// Round 2
// 2995.994 us; speedup vs baseline: 1.4938x; 1.4938x over previous
//
#include <hip/hip_runtime.h>
#include <cstdint>
#include <cstddef>

// B=32, S=512, I=256, H=512, E=1024, NH=16, HD=64
// Structural collapse (verified): only attention head 15 at s in [496,512)
// reaches the FC head; backward LSTM needs only its first 16 steps; Wo/Wfc
// fold to w_eff; w_eff-contracted Wv folds to wv2.
// Round 2 change: NO __threadfence() on the step critical path. All cross-WG
// data (h double buffers, hist, logits) moves via agent-scope atomics
// (coherent at LLC, bypass L1/L2), ordering via the vmcnt drain that
// __syncthreads performs before the counter bump. x slice prefetched into
// registers before the spin-wait.

typedef _Float16 v8h __attribute__((ext_vector_type(8)));
typedef _Float16 v4h __attribute__((ext_vector_type(4)));
typedef float    v4f __attribute__((ext_vector_type(4)));

#define AT_LD(p)     __hip_atomic_load((p), __ATOMIC_RELAXED, __HIP_MEMORY_SCOPE_AGENT)
#define AT_ST(p, v)  __hip_atomic_store((p), (v), __ATOMIC_RELAXED, __HIP_MEMORY_SCOPE_AGENT)

// ---- workspace layout (bytes), all offsets 256B aligned ----
static constexpr size_t OFF_CNT   = 0;                        // 3 x u32: cnt_f, cnt_b, done
static constexpr size_t OFF_LOGIT = 256;                      // 32 floats
static constexpr size_t OFF_HFB   = 1024;                     // fwd h dbl buf: 2*32*512 f16
static constexpr size_t OFF_HBB   = 66560;                    // bwd h dbl buf
static constexpr size_t ZERO_BYTES= 132096;                   // memset span
static constexpr size_t OFF_WHHF  = 132096;                   // 2048x512 f16
static constexpr size_t OFF_WIHF  = OFF_WHHF + 2048ull*512*2; // 2048x256 f16
static constexpr size_t OFF_WHHB  = OFF_WIHF + 2048ull*256*2;
static constexpr size_t OFF_WIHB  = OFF_WHHB + 2048ull*512*2;
static constexpr size_t OFF_HIST  = OFF_WIHB + 2048ull*256*2; // 32*16*1024 f32
static constexpr size_t OFF_WKT   = OFF_HIST + 32ull*16*1024*4;  // 1024x1024 f16 (WkT[e][j])
static constexpr size_t OFF_WQT   = OFF_WKT + 1024ull*1024*2;    // 1024x64 f16 (WqT15[e][d])
static constexpr size_t OFF_WV2   = OFF_WQT + 1024ull*64*2;      // 16*1024*16 f32 wv2T[r][e][kh]
static constexpr size_t OFF_CV    = OFF_WV2 + 16ull*1024*16*4;   // 16*16 f32
static constexpr size_t OFF_BEFF  = OFF_CV + 1024;               // 1 f32
static constexpr size_t OFF_WEFF  = OFF_BEFF + 256;              // 1024 f32
// total ~11.3 MB

static constexpr int PANEL_STRIDE = 776;   // 768 + 8 f16 pad (bank de-phase)
static constexpr int DYN_LDS      = 53504;

// -------------------- prep kernels --------------------

__global__ void k_convert(const float* __restrict__ whhf, const float* __restrict__ wihf,
                          const float* __restrict__ whhb, const float* __restrict__ wihb,
                          char* __restrict__ ws)
{
    _Float16* o1 = (_Float16*)(ws + OFF_WHHF);
    _Float16* o2 = (_Float16*)(ws + OFF_WIHF);
    _Float16* o3 = (_Float16*)(ws + OFF_WHHB);
    _Float16* o4 = (_Float16*)(ws + OFF_WIHB);
    const int stride = gridDim.x * blockDim.x;
    for (int i = blockIdx.x*blockDim.x + threadIdx.x; i < 2048*512; i += stride) {
        o1[i] = (_Float16)whhf[i];
        o3[i] = (_Float16)whhb[i];
    }
    for (int i = blockIdx.x*blockDim.x + threadIdx.x; i < 2048*256; i += stride) {
        o2[i] = (_Float16)wihf[i];
        o4[i] = (_Float16)wihb[i];
    }
}

// w_eff[e2] = sum_e Wfc[e]*Wo[e][e2];  b_eff = Wfc.bo + bfc
__global__ void k_weff(const float* __restrict__ Wfc, const float* __restrict__ Wo,
                       const float* __restrict__ bo, const float* __restrict__ bfc,
                       char* __restrict__ ws)
{
    float* weff = (float*)(ws + OFF_WEFF);
    float* beff = (float*)(ws + OFF_BEFF);
    const int e2 = blockIdx.x*256 + threadIdx.x;   // grid 4 -> 1024
    float a = 0.f;
    for (int e = 0; e < 1024; ++e) a += Wfc[e] * Wo[(size_t)e*1024 + e2];
    weff[e2] = a;
    if (e2 == 0) {
        float b = bfc[0];
        for (int e = 0; e < 1024; ++e) b += Wfc[e]*bo[e];
        beff[0] = b;
    }
}

// wv2T[r][e][kh] = sum_hd w_eff[64r+hd]*Wv[64kh+hd][e];  cv[r][kh] = w_eff slice . bv slice
__global__ void k_wv2(const float* __restrict__ Wv, const float* __restrict__ bv,
                      char* __restrict__ ws)
{
    const float* weff = (const float*)(ws + OFF_WEFF);
    float* wv2 = (float*)(ws + OFF_WV2);
    float* cv  = (float*)(ws + OFF_CV);
    const int gid = blockIdx.x*256 + threadIdx.x;  // grid 64 -> 16384
    const int e = gid >> 4, kh = gid & 15;
    float col[64];
    for (int hd = 0; hd < 64; ++hd) col[hd] = Wv[((size_t)(kh*64 + hd))*1024 + e];
    for (int r = 0; r < 16; ++r) {
        float a = 0.f;
        for (int hd = 0; hd < 64; ++hd) a += weff[r*64 + hd] * col[hd];
        wv2[((size_t)r*1024 + e)*16 + kh] = a;
    }
    if (gid < 256) {
        const int r2 = gid >> 4, k2 = gid & 15;
        float a = 0.f;
        for (int hd = 0; hd < 64; ++hd) a += weff[r2*64 + hd] * bv[k2*64 + hd];
        cv[gid] = a;
    }
}

// WkT[e][j] = Wk[j][e], fp16
__global__ void k_tk(const float* __restrict__ Wk, char* __restrict__ ws)
{
    _Float16* WkT = (_Float16*)(ws + OFF_WKT);
    __shared__ float tile[32][33];
    const int jt = blockIdx.x & 31, et = blockIdx.x >> 5;   // 1024 blocks
    const int tx = threadIdx.x & 31, ty = threadIdx.x >> 5; // 32x8
    for (int i = 0; i < 4; ++i)
        tile[ty + 8*i][tx] = Wk[((size_t)(jt*32 + ty + 8*i))*1024 + et*32 + tx];
    __syncthreads();
    for (int i = 0; i < 4; ++i)
        WkT[((size_t)(et*32 + ty + 8*i))*1024 + jt*32 + tx] = (_Float16)tile[tx][ty + 8*i];
}

// WqT15[e][d] = Wq[960+d][e], fp16
__global__ void k_tq(const float* __restrict__ Wq, char* __restrict__ ws)
{
    _Float16* WqT = (_Float16*)(ws + OFF_WQT);
    const int gid = blockIdx.x*256 + threadIdx.x;  // 256 blocks -> 65536
    const int d = gid & 63, e = gid >> 6;
    WqT[e*64 + d] = (_Float16)Wq[((size_t)(960 + d))*1024 + e];
}

// -------------------- main persistent kernel --------------------
// grid = 64 WGs x 256 threads. WG 0..31: forward LSTM (512 steps),
// WG 32..63: backward LSTM (16 steps). Each WG owns 16 h-columns.
// Then all 64 WGs compute the collapsed attention epilogue.

__global__ __launch_bounds__(256, 1)
void bilstm_main(const float* __restrict__ xg,
                 const float* __restrict__ b_f, const float* __restrict__ b_b,
                 const float* __restrict__ bq,  const float* __restrict__ bk,
                 char* __restrict__ ws, float* __restrict__ out)
{
    extern __shared__ char smem[];

    const int tid  = threadIdx.x;
    const int wgid = blockIdx.x;
    const int wave = tid >> 6;
    const int lane = tid & 63;
    const int quad = lane >> 4;
    const int l16  = lane & 15;
    const int dir  = wgid >> 5;            // 0 fwd, 1 bwd
    const int col0 = (wgid & 31) * 16;

    unsigned* cnts  = (unsigned*)(ws + OFF_CNT);
    float*   logits = (float*)(ws + OFF_LOGIT);
    _Float16* hbase = (_Float16*)(ws + (dir ? OFF_HBB : OFF_HFB));
    const _Float16* whh = (const _Float16*)(ws + (dir ? OFF_WHHB : OFF_WHHF));
    const _Float16* wih = (const _Float16*)(ws + (dir ? OFF_WIHB : OFF_WIHF));
    float* hist = (float*)(ws + OFF_HIST);
    unsigned* cnt = cnts + dir;

    _Float16* panel = (_Float16*)smem;     // [32][776] f16 A-panel; gates alias it
    float* gates = (float*)smem;           // [64][132] f32: [n][b*4 + wave]

    // persistent B fragments: W rows (gate nt) x K=768 ([Whh | Wih]), wave = K-quarter
    v8h bfrag[4][6];
#pragma unroll
    for (int nt = 0; nt < 4; ++nt)
#pragma unroll
        for (int kk = 0; kk < 6; ++kk) {
            const int kb = (wave*6 + kk)*32 + quad*8;
            const int r  = nt*512 + col0 + l16;
            const _Float16* src = (kb < 512) ? (whh + (size_t)r*512 + kb)
                                             : (wih + (size_t)r*256 + (kb - 512));
            bfrag[nt][kk] = *(const v8h*)src;
        }

    // activation role: column ac = tid&15, batches ab and ab+16
    const float* bias = dir ? b_b : b_f;
    const int ac = tid & 15;
    const int ab = tid >> 4;
    float bia[4];
#pragma unroll
    for (int g = 0; g < 4; ++g) bia[g] = bias[g*512 + col0 + ac];

    float cst[2] = {0.f, 0.f};
    const int nsteps  = dir ? 16 : 512;
    const int histoff = dir ? 512 : 0;

    for (int t = 0; t < nsteps; ++t) {
        const int s = dir ? (511 - t) : t;

        // prefetch x[:, s, :] into registers (overlaps the barrier wait; x is
        // read-only input, plain cached loads are fine)
        float4 xv[8];
#pragma unroll
        for (int i = 0; i < 8; ++i) {
            const int ch = tid + 256*i; const int b = ch >> 6, ic = ch & 63;
            xv[i] = *(const float4*)(xg + ((size_t)b*512 + s)*256 + ic*4);
        }

        // barrier: wait for all 32 WGs of this direction to finish step t-1.
        // No fence needed: all cross-WG data moves via agent-scope atomics.
        if (tid == 0) {
            const unsigned target = 32u * (unsigned)t;
            while (AT_LD(cnt) < target) {}
        }
        __syncthreads();

        // stage h_{t-1} into panel cols [0,512): agent-scope u64 atomic loads
        // (coherent at LLC; producers wrote with agent-scope u32 stores)
        {
            const unsigned long long* rbuf =
                (const unsigned long long*)(hbase + ((size_t)((t+1)&1))*(32*512));
            unsigned long long hreg[16];
#pragma unroll
            for (int i = 0; i < 16; ++i) {
                const int ch = tid + 256*i;            // 4096 u64 chunks = 32 KB
                const int b = ch >> 7, kc = ch & 127;
                hreg[i] = AT_LD(rbuf + b*128 + kc);
            }
#pragma unroll
            for (int i = 0; i < 16; ++i) {
                const int ch = tid + 256*i;
                const int b = ch >> 7, kc = ch & 127;
                *(unsigned long long*)(panel + b*PANEL_STRIDE + kc*4) = hreg[i];
            }
        }
        // stage x (f32 regs -> f16) into panel cols [512,768)
#pragma unroll
        for (int i = 0; i < 8; ++i) {
            const int ch = tid + 256*i; const int b = ch >> 6, ic = ch & 63;
            v4h hx = { (_Float16)xv[i].x, (_Float16)xv[i].y,
                       (_Float16)xv[i].z, (_Float16)xv[i].w };
            *(v4h*)(panel + b*PANEL_STRIDE + 512 + ic*4) = hx;
        }
        __syncthreads();

        // GEMM: gates[b(32)][n(64)] += A[b][k(768)] * W[n][k], K split 4-way by wave
        v4f acc[2][4];
#pragma unroll
        for (int mt = 0; mt < 2; ++mt)
#pragma unroll
            for (int nt = 0; nt < 4; ++nt) { v4f z = {0.f,0.f,0.f,0.f}; acc[mt][nt] = z; }
#pragma unroll
        for (int kk = 0; kk < 6; ++kk) {
            const int kb = (wave*6 + kk)*32 + quad*8;
            const v8h a0 = *(const v8h*)(panel + l16*PANEL_STRIDE + kb);
            const v8h a1 = *(const v8h*)(panel + (16 + l16)*PANEL_STRIDE + kb);
#pragma unroll
            for (int nt = 0; nt < 4; ++nt) {
                acc[0][nt] = __builtin_amdgcn_mfma_f32_16x16x32_f16(a0, bfrag[nt][kk], acc[0][nt], 0, 0, 0);
                acc[1][nt] = __builtin_amdgcn_mfma_f32_16x16x32_f16(a1, bfrag[nt][kk], acc[1][nt], 0, 0, 0);
            }
        }
        __syncthreads();   // panel reads done before gates alias-write

        // write K-partials: gates[n][b][wave], n-stride 132 floats
#pragma unroll
        for (int mt = 0; mt < 2; ++mt)
#pragma unroll
            for (int nt = 0; nt < 4; ++nt)
#pragma unroll
                for (int r = 0; r < 4; ++r)
                    gates[(nt*16 + l16)*132 + (mt*16 + quad*4 + r)*4 + wave] = acc[mt][nt][r];
        __syncthreads();

        // activations: thread owns (b=ab, c=ac) and (b=ab+16, c=ac)
        _Float16* wbuf = hbase + ((size_t)(t&1))*(32*512);
        unsigned hb[2];
#pragma unroll
        for (int hh = 0; hh < 2; ++hh) {
            const int b = ab + 16*hh;
            float g[4];
#pragma unroll
            for (int gi = 0; gi < 4; ++gi) {
                const v4f v = *(const v4f*)(gates + (gi*16 + ac)*132 + b*4);
                g[gi] = v.x + v.y + v.z + v.w + bia[gi];
            }
            const float ig = 1.f/(1.f + __expf(-g[0]));
            const float fg = 1.f/(1.f + __expf(-g[1]));
            const float gg = 1.f - 2.f/(__expf(2.f*g[2]) + 1.f);
            const float og = 1.f/(1.f + __expf(-g[3]));
            cst[hh] = fg*cst[hh] + ig*gg;
            const float hn = og * (1.f - 2.f/(__expf(2.f*cst[hh]) + 1.f));
            hb[hh] = (unsigned)__builtin_bit_cast(unsigned short, (_Float16)hn);
            if (s >= 496)
                AT_ST(hist + ((size_t)b*16 + (s - 496))*1024 + histoff + col0 + ac, hn);
        }
        // pack adjacent columns (ac even/odd pair via shfl) -> u32 agent stores
        {
            const unsigned ot0 = (unsigned)__shfl_xor((int)hb[0], 1);
            const unsigned ot1 = (unsigned)__shfl_xor((int)hb[1], 1);
            if ((ac & 1) == 0) {
                AT_ST((unsigned*)(wbuf + (size_t)ab*512 + col0 + ac), hb[0] | (ot0 << 16));
                AT_ST((unsigned*)(wbuf + (size_t)(ab+16)*512 + col0 + ac), hb[1] | (ot1 << 16));
            }
        }
        __syncthreads();   // drains vmcnt for all waves before release
        if (tid == 0)
            __hip_atomic_fetch_add(cnt, 1u, __ATOMIC_RELAXED, __HIP_MEMORY_SCOPE_AGENT);
    }

    // join: wait for both directions fully done
    if (tid == 0) {
        while (AT_LD(cnts + 0) < 32u*512u || AT_LD(cnts + 1) < 32u*16u) {}
    }
    __syncthreads();

    // ---------------- collapsed attention epilogue ----------------
    // pairs p = 8*wgid .. 8*wgid+7;  p -> (b = p>>4, r = p&15, s' = 496+r)
    float*    hv  = (float*)smem;                 // [8][1024]
    _Float16* k16 = (_Float16*)(smem + 32768);    // [8][1024]
    float*    qb  = (float*)(smem + 49152);       // [8][64]
    float*    vzb = (float*)(smem + 51200);       // [8][16]
    float*    scb = (float*)(smem + 51712);       // [8][16]
    int*      lastf = (int*)(smem + 53248);

    const _Float16* WkT = (const _Float16*)(ws + OFF_WKT);
    const _Float16* WqT = (const _Float16*)(ws + OFF_WQT);
    const float* wv2 = (const float*)(ws + OFF_WV2);
    const float* cv  = (const float*)(ws + OFF_CV);
    const float* beff= (const float*)(ws + OFF_BEFF);

    const int p0 = wgid * 8;
    {
        const unsigned long long* hist64 = (const unsigned long long*)hist;
#pragma unroll
        for (int i = 0; i < 16; ++i) {
            const int ch = tid + 256*i;            // 4096 u64 chunks
            const int pp = ch >> 9, e2 = ch & 511;
            const int p = p0 + pp; const int b = p >> 4, r = p & 15;
            const unsigned long long w = AT_LD(hist64 + ((size_t)b*16 + r)*512 + e2);
            *(unsigned long long*)(hv + pp*1024 + e2*2) = w;
        }
    }
    __syncthreads();

    // K projection: k[pp][j] over j = jj*256+tid
    float kacc[4][8];
#pragma unroll
    for (int jj = 0; jj < 4; ++jj) {
        const float bkv = bk[jj*256 + tid];
#pragma unroll
        for (int pp = 0; pp < 8; ++pp) kacc[jj][pp] = bkv;
    }
    for (int e = 0; e < 1024; ++e) {
        float hvv[8];
#pragma unroll
        for (int pp = 0; pp < 8; ++pp) hvv[pp] = hv[pp*1024 + e];
#pragma unroll
        for (int jj = 0; jj < 4; ++jj) {
            const float w = (float)WkT[(size_t)e*1024 + jj*256 + tid];
#pragma unroll
            for (int pp = 0; pp < 8; ++pp) kacc[jj][pp] += w * hvv[pp];
        }
    }
#pragma unroll
    for (int jj = 0; jj < 4; ++jj)
#pragma unroll
        for (int pp = 0; pp < 8; ++pp)
            k16[pp*1024 + jj*256 + tid] = (_Float16)kacc[jj][pp];

    // Q head 15
    {
        const int d = tid & 63, ph = tid >> 6;
        float a0 = bq[960 + d], a1 = a0;
        for (int e = 0; e < 1024; ++e) {
            const float w = (float)WqT[e*64 + d];
            a0 += w * hv[ph*1024 + e];
            a1 += w * hv[(ph+4)*1024 + e];
        }
        qb[ph*64 + d] = a0;
        qb[(ph+4)*64 + d] = a1;
    }
    // vz[pp][kh] = cv + sum_e wv2T[r][e][kh]*hv[pp][e]
    if (tid < 128) {
        const int pp = tid >> 4, kh = tid & 15;
        const int r = (p0 + pp) & 15;
        float a = cv[r*16 + kh];
        for (int e = 0; e < 1024; ++e)
            a += wv2[((size_t)r*1024 + e)*16 + kh] * hv[pp*1024 + e];
        vzb[pp*16 + kh] = a;
    }
    __syncthreads();
    // scores
    if (tid < 128) {
        const int pp = tid >> 4, kh = tid & 15;
        float a = 0.f;
#pragma unroll
        for (int d = 0; d < 64; ++d)
            a += qb[pp*64 + d] * (float)k16[pp*1024 + kh*64 + d];
        scb[pp*16 + kh] = a * 0.125f;  // 1/sqrt(64)
    }
    __syncthreads();
    // softmax over kh + contract with vz, accumulate into logits[b]
    if (tid < 8) {
        const int base = tid*16;
        float m = scb[base];
        for (int kh = 1; kh < 16; ++kh) m = fmaxf(m, scb[base+kh]);
        float sum = 0.f, wz = 0.f;
        for (int kh = 0; kh < 16; ++kh) {
            const float pe = __expf(scb[base+kh] - m);
            sum += pe; wz += pe * vzb[base+kh];
        }
        atomicAdd(&logits[(p0 + tid) >> 4], wz / sum);
    }
    __syncthreads();  // drains the atomics (vmcnt) before done-count
    if (tid == 0) {
        const unsigned old = __hip_atomic_fetch_add(cnts + 2, 1u, __ATOMIC_RELAXED, __HIP_MEMORY_SCOPE_AGENT);
        *lastf = (old == 63u) ? 1 : 0;
    }
    __syncthreads();
    if (*lastf) {                       // WG-uniform branch
        if (tid < 32) {
            const float lg = AT_LD(logits + tid) + beff[0];
            out[tid] = 1.f/(1.f + __expf(-lg));
        }
    }
}

// -------------------- launcher --------------------

extern "C" void kernel_launch(void* const* d_in, const int* in_sizes, int n_in,
                              void* d_out, int out_size, void* d_ws, size_t ws_size,
                              hipStream_t stream)
{
    (void)in_sizes; (void)n_in; (void)out_size; (void)ws_size;
    const float* x    = (const float*)d_in[0];
    const float* Wihf = (const float*)d_in[1];
    const float* Whhf = (const float*)d_in[2];
    const float* b_f  = (const float*)d_in[3];
    const float* Wihb = (const float*)d_in[4];
    const float* Whhb = (const float*)d_in[5];
    const float* b_b  = (const float*)d_in[6];
    const float* Wq   = (const float*)d_in[7];
    const float* bq   = (const float*)d_in[8];
    const float* Wk   = (const float*)d_in[9];
    const float* bk   = (const float*)d_in[10];
    const float* Wv   = (const float*)d_in[11];
    const float* bv   = (const float*)d_in[12];
    const float* Wo   = (const float*)d_in[13];
    const float* bo   = (const float*)d_in[14];
    const float* Wfc  = (const float*)d_in[15];
    const float* bfc  = (const float*)d_in[16];
    char* ws = (char*)d_ws;
    float* out = (float*)d_out;

    // zero counters + logits + h double buffers (ws is poisoned 0xAA each call)
    hipMemsetAsync(ws, 0, ZERO_BYTES, stream);
    hipLaunchKernelGGL(k_convert, dim3(512), dim3(256), 0, stream, Whhf, Wihf, Whhb, Wihb, ws);
    hipLaunchKernelGGL(k_weff,    dim3(4),   dim3(256), 0, stream, Wfc, Wo, bo, bfc, ws);
    hipLaunchKernelGGL(k_wv2,     dim3(64),  dim3(256), 0, stream, Wv, bv, ws);
    hipLaunchKernelGGL(k_tk,      dim3(1024),dim3(256), 0, stream, Wk, ws);
    hipLaunchKernelGGL(k_tq,      dim3(256), dim3(256), 0, stream, Wq, ws);
    hipLaunchKernelGGL(bilstm_main, dim3(64), dim3(256), DYN_LDS, stream,
                       x, b_f, b_b, bq, bk, ws, out);
}

// Round 3
// 1853.499 us; speedup vs baseline: 2.4146x; 1.6164x over previous
//
#include <hip/hip_runtime.h>
#include <cstdint>
#include <cstddef>

// B=32, S=512, I=256, H=512, E=1024, NH=16, HD=64
// Structural collapse (verified): only attention head 15 at s in [496,512)
// reaches the FC head; backward LSTM needs only its first 16 steps; Wo/Wfc
// fold to w_eff; w_eff-contracted Wv folds to wv2.
// Round 3: barrier-free LSTM. 128 WGs = 4 batch-groups x 32 col-groups.
// Full h history (one fresh 32KB slot per step) pre-filled with 0xFFFF
// sentinel (impossible f16 output of og*tanh(c)); consumers poll the data
// itself via agent-scope atomic loads. No counters/fences on the step path.

typedef _Float16 v8h __attribute__((ext_vector_type(8)));
typedef _Float16 v4h __attribute__((ext_vector_type(4)));
typedef float    v4f __attribute__((ext_vector_type(4)));

#define AT_LD(p)     __hip_atomic_load((p), __ATOMIC_RELAXED, __HIP_MEMORY_SCOPE_AGENT)
#define AT_ST(p, v)  __hip_atomic_store((p), (v), __ATOMIC_RELAXED, __HIP_MEMORY_SCOPE_AGENT)

// ---- workspace layout (bytes) ----
static constexpr size_t OFF_CNT   = 0;        // 3 x u32: lstm-done, -, epi-done
static constexpr size_t OFF_LOGIT = 256;      // 32 f32
static constexpr size_t OFF_BEFF  = 512;      // 1 f32
static constexpr size_t OFF_WEFF  = 1024;     // 1024 f32
static constexpr size_t OFF_HF    = 8192;     // h_f[513][32][512] f16 (slot = s+1)
static constexpr size_t HF_BYTES  = 513ull*32768;
static constexpr size_t OFF_HB    = OFF_HF + HF_BYTES;   // h_b[17][32][512] f16
static constexpr size_t HB_BYTES  = 17ull*32768;
static constexpr size_t OFF_WHHF  = OFF_HB + HB_BYTES;   // 2048x512 f16
static constexpr size_t OFF_WIHF  = OFF_WHHF + 2048ull*512*2;
static constexpr size_t OFF_WHHB  = OFF_WIHF + 2048ull*256*2;
static constexpr size_t OFF_WIHB  = OFF_WHHB + 2048ull*512*2;
static constexpr size_t OFF_WKT   = OFF_WIHB + 2048ull*256*2;   // 1024x1024 f16
static constexpr size_t OFF_WQT   = OFF_WKT + 1024ull*1024*2;   // 1024x64 f16
static constexpr size_t OFF_WV2   = OFF_WQT + 1024ull*64*2;     // 16*1024*16 f32
static constexpr size_t OFF_CV    = OFF_WV2 + 16ull*1024*16*4;  // 256 f32
// total ~25.7 MiB

static constexpr int PSTR    = 776;                 // panel stride (f16)
static constexpr int GSTR    = 68;                  // gates stride (f32)
static constexpr int LDS_PANEL_B = 16*PSTR*2;       // 24832
static constexpr int DYN_LDS = LDS_PANEL_B + 64*GSTR*4;  // 24832+17408 = 42240

__device__ __forceinline__ bool has_ffff(unsigned long long w) {
    return ((w & 0xFFFFull) == 0xFFFFull) ||
           (((w >> 16) & 0xFFFFull) == 0xFFFFull) ||
           (((w >> 32) & 0xFFFFull) == 0xFFFFull) ||
           ((w >> 48) == 0xFFFFull);
}

// -------------------- prep kernels --------------------

__global__ void k_convert(const float* __restrict__ whhf, const float* __restrict__ wihf,
                          const float* __restrict__ whhb, const float* __restrict__ wihb,
                          char* __restrict__ ws)
{
    _Float16* o1 = (_Float16*)(ws + OFF_WHHF);
    _Float16* o2 = (_Float16*)(ws + OFF_WIHF);
    _Float16* o3 = (_Float16*)(ws + OFF_WHHB);
    _Float16* o4 = (_Float16*)(ws + OFF_WIHB);
    const int stride = gridDim.x * blockDim.x;
    for (int i = blockIdx.x*blockDim.x + threadIdx.x; i < 2048*512; i += stride) {
        o1[i] = (_Float16)whhf[i];
        o3[i] = (_Float16)whhb[i];
    }
    for (int i = blockIdx.x*blockDim.x + threadIdx.x; i < 2048*256; i += stride) {
        o2[i] = (_Float16)wihf[i];
        o4[i] = (_Float16)wihb[i];
    }
}

// weff[e2] += partial(Wfc . Wo[:,e2]); beff += partial(Wfc . bo) (+bfc once)
__global__ void k_weff(const float* __restrict__ Wfc, const float* __restrict__ Wo,
                       const float* __restrict__ bo, const float* __restrict__ bfc,
                       char* __restrict__ ws)
{
    float* weff = (float*)(ws + OFF_WEFF);
    float* beff = (float*)(ws + OFF_BEFF);
    const int bid = blockIdx.x;                 // 64 blocks
    const int e2 = (bid & 3)*256 + threadIdx.x;
    const int slab = bid >> 2;                  // 16 slabs of 64 e
    float a = 0.f;
    for (int e = slab*64; e < slab*64 + 64; ++e)
        a += Wfc[e] * Wo[(size_t)e*1024 + e2];
    atomicAdd(weff + e2, a);
    if ((bid & 3) == 0 && threadIdx.x < 64) {
        const int e = slab*64 + threadIdx.x;
        float b = Wfc[e]*bo[e];
        if (bid == 0 && threadIdx.x == 0) b += bfc[0];
        atomicAdd(beff, b);
    }
}

// wv2[(r*1024+e)*16+kh] = sum_hd weff[r*64+hd]*Wv[(kh*64+hd)*1024+e]; cv
__global__ void k_wv2(const float* __restrict__ Wv, const float* __restrict__ bv,
                      char* __restrict__ ws)
{
    const float* weff = (const float*)(ws + OFF_WEFF);
    float* wv2 = (float*)(ws + OFF_WV2);
    float* cv  = (float*)(ws + OFF_CV);
    const int bid = blockIdx.x;                 // 65 blocks
    if (bid < 64) {
        const int r = bid >> 2;
        const int e = (bid & 3)*256 + threadIdx.x;
        for (int kh = 0; kh < 16; ++kh) {
            float a = 0.f;
            for (int hd = 0; hd < 64; ++hd)
                a += weff[r*64 + hd] * Wv[((size_t)(kh*64 + hd))*1024 + e];
            wv2[((size_t)r*1024 + e)*16 + kh] = a;
        }
    } else {
        const int r2 = threadIdx.x >> 4, k2 = threadIdx.x & 15;
        float a = 0.f;
        for (int hd = 0; hd < 64; ++hd)
            a += weff[r2*64 + hd] * bv[k2*64 + hd];
        cv[threadIdx.x] = a;
    }
}

// WkT[e][j] = Wk[j][e], fp16
__global__ void k_tk(const float* __restrict__ Wk, char* __restrict__ ws)
{
    _Float16* WkT = (_Float16*)(ws + OFF_WKT);
    __shared__ float tile[32][33];
    const int jt = blockIdx.x & 31, et = blockIdx.x >> 5;   // 1024 blocks
    const int tx = threadIdx.x & 31, ty = threadIdx.x >> 5; // 32x8
    for (int i = 0; i < 4; ++i)
        tile[ty + 8*i][tx] = Wk[((size_t)(jt*32 + ty + 8*i))*1024 + et*32 + tx];
    __syncthreads();
    for (int i = 0; i < 4; ++i)
        WkT[((size_t)(et*32 + ty + 8*i))*1024 + jt*32 + tx] = (_Float16)tile[tx][ty + 8*i];
}

// WqT15[e][d] = Wq[960+d][e], fp16
__global__ void k_tq(const float* __restrict__ Wq, char* __restrict__ ws)
{
    _Float16* WqT = (_Float16*)(ws + OFF_WQT);
    const int gid = blockIdx.x*256 + threadIdx.x;  // 256 blocks
    const int d = gid & 63, e = gid >> 6;
    WqT[e*64 + d] = (_Float16)Wq[((size_t)(960 + d))*1024 + e];
}

// -------------------- main persistent kernel --------------------
// 128 WGs x 256 threads. group g = wgid>>5 (8 batches), colgroup = wgid&31
// (16 h-cols). Phase 0: bwd 16 steps; phase 1: fwd 512 steps. Sentinel
// data-polling; no global barrier until the pre-epilogue join.

__global__ __launch_bounds__(256, 1)
void bilstm_main(const float* __restrict__ xg,
                 const float* __restrict__ b_f, const float* __restrict__ b_b,
                 const float* __restrict__ bq,  const float* __restrict__ bk,
                 char* __restrict__ ws, float* __restrict__ out)
{
    extern __shared__ char smem[];
    _Float16* panel = (_Float16*)smem;                   // [16][776]
    float* gates = (float*)(smem + LDS_PANEL_B);         // [64][68]

    const int tid  = threadIdx.x;
    const int wgid = blockIdx.x;
    const int wave = tid >> 6;
    const int lane = tid & 63;
    const int quad = lane >> 4;
    const int l16  = lane & 15;
    const int grp  = wgid >> 5;            // batch group (8 batches)
    const int col0 = (wgid & 31) * 16;

    unsigned* cnts  = (unsigned*)(ws + OFF_CNT);
    float*   logits = (float*)(ws + OFF_LOGIT);

    // activation role (tid < 128): batch b = tid>>4 in [0,8), col c = tid&15
    const int ac = tid & 15;
    const int ab = tid >> 4;

    for (int phase = 0; phase < 2; ++phase) {
        const int dir     = phase == 0 ? 1 : 0;       // bwd first
        const int nsteps  = dir ? 16 : 512;
        char* hslab = ws + (dir ? OFF_HB : OFF_HF);
        const _Float16* whh = (const _Float16*)(ws + (dir ? OFF_WHHB : OFF_WHHF));
        const _Float16* wih = (const _Float16*)(ws + (dir ? OFF_WIHB : OFF_WIHF));
        const float* bias = dir ? b_b : b_f;

        // persistent B fragments: rows (gate nt, col l16) x K=768, wave = K-quarter
        v8h bfrag[4][6];
#pragma unroll
        for (int nt = 0; nt < 4; ++nt)
#pragma unroll
            for (int kk = 0; kk < 6; ++kk) {
                const int kb = (wave*6 + kk)*32 + quad*8;
                const int r  = nt*512 + col0 + l16;
                const _Float16* src = (kb < 512) ? (whh + (size_t)r*512 + kb)
                                                 : (wih + (size_t)r*256 + (kb - 512));
                bfrag[nt][kk] = *(const v8h*)src;
            }
        float bia[4];
#pragma unroll
        for (int g = 0; g < 4; ++g) bia[g] = bias[g*512 + col0 + ac];

        float cst = 0.f;

        for (int t = 0; t < nsteps; ++t) {
            const int s = dir ? (511 - t) : t;

            // prefetch x[group batches][s][:] into registers
            float4 xv[2];
#pragma unroll
            for (int i = 0; i < 2; ++i) {
                const int ch = tid + 256*i;           // [0,512)
                const int b = ch >> 6, ic = ch & 63;
                xv[i] = *(const float4*)(xg + ((size_t)(grp*8 + b)*512 + s)*256 + ic*4);
            }

            // gather h_{t-1} (slot t) by polling the data sentinel
            {
                const int b = tid >> 5, seg = tid & 31;   // 8 KB: 8 b x 512 cols
                const unsigned long long* src = (const unsigned long long*)hslab
                    + (size_t)t*4096 + (size_t)(grp*8 + b)*128 + seg*4;
                unsigned long long w0, w1, w2, w3;
                for (;;) {
                    w0 = AT_LD(src + 0); w1 = AT_LD(src + 1);
                    w2 = AT_LD(src + 2); w3 = AT_LD(src + 3);
                    if (!(has_ffff(w0) || has_ffff(w1) || has_ffff(w2) || has_ffff(w3)))
                        break;
                    __builtin_amdgcn_s_sleep(1);
                }
                unsigned long long* dst = (unsigned long long*)(panel + b*PSTR + seg*16);
                dst[0] = w0; dst[1] = w1; dst[2] = w2; dst[3] = w3;
            }
            // x (f32 regs -> f16) into panel cols [512,768)
#pragma unroll
            for (int i = 0; i < 2; ++i) {
                const int ch = tid + 256*i;
                const int b = ch >> 6, ic = ch & 63;
                v4h hx = { (_Float16)xv[i].x, (_Float16)xv[i].y,
                           (_Float16)xv[i].z, (_Float16)xv[i].w };
                *(v4h*)(panel + b*PSTR + 512 + ic*4) = hx;
            }
            __syncthreads();   // S_a: panel ready

            // GEMM: gates[b(8)][n(64)] = A[b][768] * W[n][768], K 4-way by wave
            v4f acc[4];
#pragma unroll
            for (int nt = 0; nt < 4; ++nt) { v4f z = {0.f,0.f,0.f,0.f}; acc[nt] = z; }
#pragma unroll
            for (int kk = 0; kk < 6; ++kk) {
                const int kb = (wave*6 + kk)*32 + quad*8;
                const v8h a0 = *(const v8h*)(panel + l16*PSTR + kb);
#pragma unroll
                for (int nt = 0; nt < 4; ++nt)
                    acc[nt] = __builtin_amdgcn_mfma_f32_16x16x32_f16(a0, bfrag[nt][kk], acc[nt], 0, 0, 0);
            }
            // K-partials (separate LDS region; panel reads complete before S_c)
#pragma unroll
            for (int nt = 0; nt < 4; ++nt)
#pragma unroll
                for (int r = 0; r < 4; ++r)
                    gates[(nt*16 + l16)*GSTR + (quad*4 + r)*4 + wave] = acc[nt][r];
            __syncthreads();   // S_c: partials ready

            // activations: tid<128, one (b, c) each
            if (tid < 128) {
                float g[4];
#pragma unroll
                for (int gi = 0; gi < 4; ++gi) {
                    const v4f v = *(const v4f*)(gates + (gi*16 + ac)*GSTR + ab*4);
                    g[gi] = v.x + v.y + v.z + v.w + bia[gi];
                }
                const float ig = 1.f/(1.f + __expf(-g[0]));
                const float fg = 1.f/(1.f + __expf(-g[1]));
                const float gg = 1.f - 2.f/(__expf(2.f*g[2]) + 1.f);
                const float og = 1.f/(1.f + __expf(-g[3]));
                cst = fg*cst + ig*gg;
                const float hn = og * (1.f - 2.f/(__expf(2.f*cst) + 1.f));
                const unsigned hb = (unsigned)__builtin_bit_cast(unsigned short, (_Float16)hn);
                const unsigned ot = (unsigned)__shfl_xor((int)hb, 1);
                if ((ac & 1) == 0) {
                    _Float16* hrow = (_Float16*)hslab
                        + ((size_t)(t+1)*32 + (grp*8 + ab))*512 + col0 + ac;
                    AT_ST((unsigned*)hrow, hb | (ot << 16));
                }
            }
            // no trailing barrier: next step's poll self-synchronizes
        }
    }

    // join before epilogue
    __syncthreads();
    if (tid == 0) {
        __hip_atomic_fetch_add(cnts + 0, 1u, __ATOMIC_RELAXED, __HIP_MEMORY_SCOPE_AGENT);
        while (AT_LD(cnts + 0) < 128u) __builtin_amdgcn_s_sleep(8);
    }
    __syncthreads();

    // ---------------- collapsed attention epilogue ----------------
    // 4 pairs per WG: p = wgid*4+pp -> (b = p>>4, r = p&15, s' = 496+r)
    float*    hv  = (float*)smem;                 // [4][1024]
    _Float16* k16 = (_Float16*)(smem + 16384);    // [4][1024]
    float*    qb  = (float*)(smem + 24576);       // [4][64]
    float*    vzb = (float*)(smem + 25600);       // [4][16]
    float*    scb = (float*)(smem + 25856);       // [4][16]
    int*      lastf = (int*)(smem + 26112);

    const _Float16* WkT = (const _Float16*)(ws + OFF_WKT);
    const _Float16* WqT = (const _Float16*)(ws + OFF_WQT);
    const float* wv2 = (const float*)(ws + OFF_WV2);
    const float* cv  = (const float*)(ws + OFF_CV);
    const float* beff= (const float*)(ws + OFF_BEFF);

    const int p0 = wgid * 4;
#pragma unroll
    for (int i = 0; i < 4; ++i) {
        const int ch = tid + 256*i;               // 1024 u64 chunks
        const int pp = ch >> 8, q = ch & 255;     // e = q*4
        const int p = p0 + pp; const int b = p >> 4; const int r = p & 15;
        unsigned long long w;
        if (q < 128)   // fwd h at s=496+r -> slot 497+r
            w = AT_LD((const unsigned long long*)(ws + OFF_HF)
                      + ((size_t)(497 + r)*32 + b)*128 + q);
        else           // bwd h at s=496+r -> slot 16-r
            w = AT_LD((const unsigned long long*)(ws + OFF_HB)
                      + ((size_t)(16 - r)*32 + b)*128 + (q - 128));
        float* dst = hv + pp*1024 + q*4;
#pragma unroll
        for (int j = 0; j < 4; ++j)
            dst[j] = (float)__builtin_bit_cast(_Float16, (unsigned short)((w >> (16*j)) & 0xFFFF));
    }
    __syncthreads();

    // K projection: k[pp][j], j = jj*256+tid
    float kacc[4][4];
#pragma unroll
    for (int jj = 0; jj < 4; ++jj) {
        const float bkv = bk[jj*256 + tid];
#pragma unroll
        for (int pp = 0; pp < 4; ++pp) kacc[jj][pp] = bkv;
    }
    for (int e = 0; e < 1024; ++e) {
        float hvv[4];
#pragma unroll
        for (int pp = 0; pp < 4; ++pp) hvv[pp] = hv[pp*1024 + e];
#pragma unroll
        for (int jj = 0; jj < 4; ++jj) {
            const float w = (float)WkT[(size_t)e*1024 + jj*256 + tid];
#pragma unroll
            for (int pp = 0; pp < 4; ++pp) kacc[jj][pp] += w * hvv[pp];
        }
    }
#pragma unroll
    for (int jj = 0; jj < 4; ++jj)
#pragma unroll
        for (int pp = 0; pp < 4; ++pp)
            k16[pp*1024 + jj*256 + tid] = (_Float16)kacc[jj][pp];

    // Q head 15: one pair per 64-lane chunk
    {
        const int d = tid & 63, ph = tid >> 6;
        float a0 = bq[960 + d];
        for (int e = 0; e < 1024; ++e)
            a0 += (float)WqT[e*64 + d] * hv[ph*1024 + e];
        qb[ph*64 + d] = a0;
    }
    // vz[pp][kh]
    if (tid < 64) {
        const int pp = tid >> 4, kh = tid & 15;
        const int r = (p0 + pp) & 15;
        float a = cv[r*16 + kh];
        for (int e = 0; e < 1024; ++e)
            a += wv2[((size_t)r*1024 + e)*16 + kh] * hv[pp*1024 + e];
        vzb[pp*16 + kh] = a;
    }
    __syncthreads();
    if (tid < 64) {
        const int pp = tid >> 4, kh = tid & 15;
        float a = 0.f;
#pragma unroll
        for (int d = 0; d < 64; ++d)
            a += qb[pp*64 + d] * (float)k16[pp*1024 + kh*64 + d];
        scb[pp*16 + kh] = a * 0.125f;
    }
    __syncthreads();
    if (tid < 4) {
        const int base = tid*16;
        float m = scb[base];
        for (int kh = 1; kh < 16; ++kh) m = fmaxf(m, scb[base+kh]);
        float sum = 0.f, wz = 0.f;
        for (int kh = 0; kh < 16; ++kh) {
            const float pe = __expf(scb[base+kh] - m);
            sum += pe; wz += pe * vzb[base+kh];
        }
        atomicAdd(&logits[(p0 + tid) >> 4], wz / sum);
    }
    __syncthreads();
    if (tid == 0) {
        const unsigned old = __hip_atomic_fetch_add(cnts + 2, 1u, __ATOMIC_RELAXED, __HIP_MEMORY_SCOPE_AGENT);
        *lastf = (old == 127u) ? 1 : 0;
    }
    __syncthreads();
    if (*lastf) {
        if (tid < 32) {
            const float lg = AT_LD(logits + tid) + beff[0];
            out[tid] = 1.f/(1.f + __expf(-lg));
        }
    }
}

// -------------------- launcher --------------------

extern "C" void kernel_launch(void* const* d_in, const int* in_sizes, int n_in,
                              void* d_out, int out_size, void* d_ws, size_t ws_size,
                              hipStream_t stream)
{
    (void)in_sizes; (void)n_in; (void)out_size; (void)ws_size;
    const float* x    = (const float*)d_in[0];
    const float* Wihf = (const float*)d_in[1];
    const float* Whhf = (const float*)d_in[2];
    const float* b_f  = (const float*)d_in[3];
    const float* Wihb = (const float*)d_in[4];
    const float* Whhb = (const float*)d_in[5];
    const float* b_b  = (const float*)d_in[6];
    const float* Wq   = (const float*)d_in[7];
    const float* bq   = (const float*)d_in[8];
    const float* Wk   = (const float*)d_in[9];
    const float* bk   = (const float*)d_in[10];
    const float* Wv   = (const float*)d_in[11];
    const float* bv   = (const float*)d_in[12];
    const float* Wo   = (const float*)d_in[13];
    const float* bo   = (const float*)d_in[14];
    const float* Wfc  = (const float*)d_in[15];
    const float* bfc  = (const float*)d_in[16];
    char* ws = (char*)d_ws;
    float* out = (float*)d_out;

    // init: counters/logits/weff/beff + h slot0 = 0; history slots = 0xFFFF sentinel
    hipMemsetAsync(ws, 0, OFF_HF + 32768, stream);                      // cnts..h_f[0]
    hipMemsetAsync(ws + OFF_HF + 32768, 0xFF, 512ull*32768, stream);    // h_f[1..512]
    hipMemsetAsync(ws + OFF_HB, 0, 32768, stream);                      // h_b[0]
    hipMemsetAsync(ws + OFF_HB + 32768, 0xFF, 16ull*32768, stream);     // h_b[1..16]

    hipLaunchKernelGGL(k_convert, dim3(512), dim3(256), 0, stream, Whhf, Wihf, Whhb, Wihb, ws);
    hipLaunchKernelGGL(k_weff,    dim3(64),  dim3(256), 0, stream, Wfc, Wo, bo, bfc, ws);
    hipLaunchKernelGGL(k_wv2,     dim3(65),  dim3(256), 0, stream, Wv, bv, ws);
    hipLaunchKernelGGL(k_tk,      dim3(1024),dim3(256), 0, stream, Wk, ws);
    hipLaunchKernelGGL(k_tq,      dim3(256), dim3(256), 0, stream, Wq, ws);
    hipLaunchKernelGGL(bilstm_main, dim3(128), dim3(256), DYN_LDS, stream,
                       x, b_f, b_b, bq, bk, ws, out);
}